// Round 1
// baseline (470.329 us; speedup 1.0000x reference)
//
#include <hip/hip_runtime.h>
#include <math.h>

// DigitCaps dynamic routing, MI355X.
// B=256 batch, I=1152 in-caps (dim 8), O=10 out-caps (dim 16), 3 routing iters.
// One workgroup per batch element (256 wgs = 1 per CU), 256 threads.
// Thread t owns input capsules i = t, t+256, ... (<=5).
// Key identity: b_ij at iter k = sum_{j<k} u.v_j  ->  logits = u . (v0+..+v_{k-1})
// so b_ij is never materialized; only a running vsum[160] per block.

constexpr int Bc  = 256;
constexpr int Ic  = 1152;
constexpr int DIc = 8;
constexpr int Oc  = 10;
constexpr int DOc = 16;
constexpr int ODc = Oc * DOc;   // 160
constexpr int TPB = 256;
constexpr int QN  = 5;          // ceil(I / TPB)

__device__ __forceinline__ float wave_bfly_sum(float v) {
    v += __shfl_xor(v, 1);
    v += __shfl_xor(v, 2);
    v += __shfl_xor(v, 4);
    v += __shfl_xor(v, 8);
    v += __shfl_xor(v, 16);
    v += __shfl_xor(v, 32);
    return v;
}

// Reduce s_part[160] across the 256-thread block, scale by `pre`,
// squash along d (16), write v into vout[160] and accumulate into vsum[160].
__device__ __forceinline__ void reduce_squash(const float* s_part, float pre,
                                              float* red, float* svec,
                                              float* vout, float* vsum,
                                              int lane, int wid, int t) {
#pragma unroll
    for (int e = 0; e < ODc; ++e) {
        float r = wave_bfly_sum(s_part[e]);
        if (lane == (e & 63)) red[wid * ODc + e] = r;
    }
    __syncthreads();
    if (t < ODc) {
        svec[t] = (red[t] + red[ODc + t] + red[2 * ODc + t] + red[3 * ODc + t]) * pre;
    }
    __syncthreads();
    if (t < Oc) {
        float sq = 0.f;
#pragma unroll
        for (int d = 0; d < DOc; ++d) {
            float s = svec[t * DOc + d];
            sq += s * s;
        }
        // v = s * sq / (1+sq) / sqrt(sq)
        float scale = sq / ((1.f + sq) * sqrtf(sq));
#pragma unroll
        for (int d = 0; d < DOc; ++d) {
            float v = svec[t * DOc + d] * scale;
            vout[t * DOc + d] = v;
            vsum[t * DOc + d] += v;
        }
    }
    __syncthreads();
}

__device__ __forceinline__ void compute_u_from_w(const float* __restrict__ W,
                                                 const float* xs, int i, float* u) {
    float xr[DIc];
#pragma unroll
    for (int k = 0; k < DIc; ++k) xr[k] = xs[i * DIc + k];
    const float4* wp = (const float4*)(W + (size_t)i * (Oc * DOc * DIc));
#pragma unroll
    for (int od = 0; od < ODc; ++od) {
        float4 w0 = wp[2 * od];
        float4 w1 = wp[2 * od + 1];
        u[od] = w0.x * xr[0] + w0.y * xr[1] + w0.z * xr[2] + w0.w * xr[3] +
                w1.x * xr[4] + w1.y * xr[5] + w1.z * xr[6] + w1.w * xr[7];
    }
}

template <bool USE_WS>
__global__ void __launch_bounds__(TPB, 1)
digitcaps_kernel(const float* __restrict__ x, const float* __restrict__ W,
                 float* __restrict__ out, float* __restrict__ uws) {
    const int b    = blockIdx.x;
    const int t    = threadIdx.x;
    const int lane = t & 63;
    const int wid  = t >> 6;

    __shared__ __align__(16) float xs[Ic * DIc];      // 36864 B
    __shared__ __align__(16) float red[4 * ODc];      //  2560 B
    __shared__ __align__(16) float svec[ODc];
    __shared__ __align__(16) float vcur[ODc];
    __shared__ __align__(16) float vsum[ODc];

    // stage x[b] into LDS (coalesced float4)
    {
        const float4* xg = (const float4*)(x + (size_t)b * (Ic * DIc));
        float4* xl = (float4*)xs;
#pragma unroll
        for (int j = 0; j < (Ic * DIc / 4) / TPB; ++j)   // 9 iters
            xl[t + j * TPB] = xg[t + j * TPB];
    }
    if (t < ODc) vsum[t] = 0.f;
    __syncthreads();

    float s_part[ODc];

    // ---------------- Pass 0: u_hat = W @ x ; s0 = 0.1 * sum_i u ----------------
#pragma unroll
    for (int e = 0; e < ODc; ++e) s_part[e] = 0.f;

#pragma unroll 1
    for (int q = 0; q < QN; ++q) {
        const int i = t + q * TPB;
        if (i < Ic) {
            float xr[DIc];
#pragma unroll
            for (int k = 0; k < DIc; ++k) xr[k] = xs[i * DIc + k];
            const float4* wp = (const float4*)(W + (size_t)i * (Oc * DOc * DIc));
            float4* up = (float4*)(uws + ((size_t)b * Ic + i) * ODc);
#pragma unroll
            for (int g = 0; g < ODc / 4; ++g) {   // 40 groups of 4 (o,d)
                float u0, u1, u2, u3;
                {
                    float4 w0 = wp[(4 * g + 0) * 2], w1 = wp[(4 * g + 0) * 2 + 1];
                    u0 = w0.x * xr[0] + w0.y * xr[1] + w0.z * xr[2] + w0.w * xr[3] +
                         w1.x * xr[4] + w1.y * xr[5] + w1.z * xr[6] + w1.w * xr[7];
                }
                {
                    float4 w0 = wp[(4 * g + 1) * 2], w1 = wp[(4 * g + 1) * 2 + 1];
                    u1 = w0.x * xr[0] + w0.y * xr[1] + w0.z * xr[2] + w0.w * xr[3] +
                         w1.x * xr[4] + w1.y * xr[5] + w1.z * xr[6] + w1.w * xr[7];
                }
                {
                    float4 w0 = wp[(4 * g + 2) * 2], w1 = wp[(4 * g + 2) * 2 + 1];
                    u2 = w0.x * xr[0] + w0.y * xr[1] + w0.z * xr[2] + w0.w * xr[3] +
                         w1.x * xr[4] + w1.y * xr[5] + w1.z * xr[6] + w1.w * xr[7];
                }
                {
                    float4 w0 = wp[(4 * g + 3) * 2], w1 = wp[(4 * g + 3) * 2 + 1];
                    u3 = w0.x * xr[0] + w0.y * xr[1] + w0.z * xr[2] + w0.w * xr[3] +
                         w1.x * xr[4] + w1.y * xr[5] + w1.z * xr[6] + w1.w * xr[7];
                }
                s_part[4 * g + 0] += u0;
                s_part[4 * g + 1] += u1;
                s_part[4 * g + 2] += u2;
                s_part[4 * g + 3] += u3;
                if (USE_WS) up[g] = make_float4(u0, u1, u2, u3);
            }
        }
    }
    reduce_squash(s_part, 0.1f, red, svec, vcur, vsum, lane, wid, t);

    // ---------------- Passes 1,2: routing iterations ----------------
#pragma unroll 1
    for (int it = 1; it < 3; ++it) {
#pragma unroll
        for (int e = 0; e < ODc; ++e) s_part[e] = 0.f;

#pragma unroll 1
        for (int q = 0; q < QN; ++q) {
            const int i = t + q * TPB;
            if (i < Ic) {
                float u[ODc];
                if (USE_WS) {
                    const float4* up =
                        (const float4*)(uws + ((size_t)b * Ic + i) * ODc);
#pragma unroll
                    for (int g = 0; g < ODc / 4; ++g) {
                        float4 uu = up[g];
                        u[4 * g + 0] = uu.x;
                        u[4 * g + 1] = uu.y;
                        u[4 * g + 2] = uu.z;
                        u[4 * g + 3] = uu.w;
                    }
                } else {
                    compute_u_from_w(W, xs, i, u);
                }
                // logits: b_ij = u . (v0 + ... + v_{it-1}) = u . vsum
                float c[Oc];
#pragma unroll
                for (int o = 0; o < Oc; ++o) {
                    float acc = 0.f;
#pragma unroll
                    for (int g = 0; g < DOc / 4; ++g) {
                        const float4 vv =
                            *((const float4*)(vsum + o * DOc + 4 * g));
                        acc += u[o * DOc + 4 * g + 0] * vv.x +
                               u[o * DOc + 4 * g + 1] * vv.y +
                               u[o * DOc + 4 * g + 2] * vv.z +
                               u[o * DOc + 4 * g + 3] * vv.w;
                    }
                    c[o] = acc;
                }
                // softmax over o (max-subtracted, as jax.nn.softmax)
                float m = c[0];
#pragma unroll
                for (int o = 1; o < Oc; ++o) m = fmaxf(m, c[o]);
                float ssum = 0.f;
#pragma unroll
                for (int o = 0; o < Oc; ++o) {
                    c[o] = expf(c[o] - m);
                    ssum += c[o];
                }
                float inv = 1.f / ssum;
#pragma unroll
                for (int o = 0; o < Oc; ++o) {
                    float co = c[o] * inv;
#pragma unroll
                    for (int d = 0; d < DOc; ++d)
                        s_part[o * DOc + d] += co * u[o * DOc + d];
                }
            }
        }
        reduce_squash(s_part, 1.f, red, svec, vcur, vsum, lane, wid, t);
    }

    if (t < ODc) out[(size_t)b * ODc + t] = vcur[t];
}

extern "C" void kernel_launch(void* const* d_in, const int* in_sizes, int n_in,
                              void* d_out, int out_size, void* d_ws, size_t ws_size,
                              hipStream_t stream) {
    (void)in_sizes; (void)n_in; (void)out_size;
    const float* x = (const float*)d_in[0];   // [256,1152,8]
    const float* W = (const float*)d_in[1];   // [1152,10,16,8]
    float* out     = (float*)d_out;           // [256,10,16]
    float* uws     = (float*)d_ws;

    const size_t need = (size_t)Bc * Ic * ODc * sizeof(float);  // ~189 MB
    dim3 grid(Bc), block(TPB);
    if (ws_size >= need) {
        hipLaunchKernelGGL((digitcaps_kernel<true>), grid, block, 0, stream,
                           x, W, out, uws);
    } else {
        hipLaunchKernelGGL((digitcaps_kernel<false>), grid, block, 0, stream,
                           x, W, out, nullptr);
    }
}

// Round 2
// 273.070 us; speedup vs baseline: 1.7224x; 1.7224x over previous
//
#include <hip/hip_runtime.h>
#include <math.h>

// DigitCaps dynamic routing, MI355X (gfx950).
// B=256, I=1152 (dim 8), O=10 (dim 16), 3 routing iters.
// Grid = 256 blocks (1/CU), block = 1024 threads (16 waves/CU).
//
// Lane mapping: t&15 = d (out dim), t>>4 = i-offset within a 64-capsule chunk.
// Per-o quantities are scalars per lane -> per-thread state ~40 floats
// (vs 320 in round 1, which spilled at VGPR=256 and ran 1 wave/SIMD).
//
// b_ij identity: logits at iter k = u . (v0+..+v_{k-1}) = u . vsum, so b_ij is
// never materialized. u_hat is stored to d_ws in (b, chunk, o, t) order so all
// global stores/loads are perfectly coalesced (4 KB per block instruction).

constexpr int Bc  = 256;
constexpr int Ic  = 1152;
constexpr int DIc = 8;
constexpr int Oc  = 10;
constexpr int DOc = 16;
constexpr int ODc = Oc * DOc;       // 160
constexpr int TPB = 1024;           // 16 waves
constexpr int NW  = TPB / 64;       // 16
constexpr int CHUNKS = Ic / 64;     // 18 (exact)

// Reduce acc[o] (per-lane, d = t&15 implicit) over i: first over the 4
// 16-lane groups in the wave, then across 16 waves via LDS. Then squash.
__device__ __forceinline__ void block_reduce_squash(
    float* acc, float pre, float* red, float* svec, float* vcur, float* vsum,
    int t, int lane, int wid) {
#pragma unroll
    for (int o = 0; o < Oc; ++o) {
        float a = acc[o];
        a += __shfl_xor(a, 16);
        a += __shfl_xor(a, 32);
        if (lane < 16) red[wid * ODc + o * DOc + lane] = a;
    }
    __syncthreads();
    if (t < ODc) {
        float s = 0.f;
#pragma unroll
        for (int w = 0; w < NW; ++w) s += red[w * ODc + t];
        svec[t] = s * pre;
    }
    __syncthreads();
    if (t < Oc) {
        float sq = 0.f;
#pragma unroll
        for (int dd = 0; dd < DOc; ++dd) {
            float s = svec[t * DOc + dd];
            sq += s * s;
        }
        float scale = sq / ((1.f + sq) * sqrtf(sq));
#pragma unroll
        for (int dd = 0; dd < DOc; ++dd) {
            float v = svec[t * DOc + dd] * scale;
            vcur[t * DOc + dd] = v;
            vsum[t * DOc + dd] += v;
        }
    }
    __syncthreads();
}

template <bool USE_WS>
__global__ void __launch_bounds__(TPB, 4)
digitcaps_kernel(const float* __restrict__ x, const float* __restrict__ W,
                 float* __restrict__ out, float* __restrict__ uws) {
    const int b    = blockIdx.x;
    const int t    = threadIdx.x;
    const int lane = t & 63;
    const int wid  = t >> 6;
    const int d    = t & 15;
    const int iblk = t >> 4;     // 0..63: i-offset within chunk

    __shared__ __align__(16) float xs[Ic * DIc];   // 36 KB
    __shared__ __align__(16) float red[NW * ODc];  // 10 KB
    __shared__ __align__(16) float svec[ODc];
    __shared__ __align__(16) float vcur[ODc];
    __shared__ __align__(16) float vsum[ODc];

    // stage x[b] into LDS, coalesced float4
    {
        const float4* xg = (const float4*)(x + (size_t)b * (Ic * DIc));
        float4* xl = (float4*)xs;
        for (int j = t; j < Ic * DIc / 4; j += TPB) xl[j] = xg[j];
    }
    if (t < ODc) vsum[t] = 0.f;
    __syncthreads();

    float acc[Oc];

    // ---------- Pass 0: u = W@x ; s0 = 0.1 * sum_i u ; store u to ws ----------
#pragma unroll
    for (int o = 0; o < Oc; ++o) acc[o] = 0.f;

#pragma unroll 1
    for (int ch = 0; ch < CHUNKS; ++ch) {
        const int i = ch * 64 + iblk;
        const float4 xa = ((const float4*)(xs + i * DIc))[0];
        const float4 xb = ((const float4*)(xs + i * DIc))[1];
        const float* wbase = W + (((size_t)i * Oc) * DOc + d) * DIc;
        float* ubase = uws + ((size_t)b * CHUNKS + ch) * (Oc * TPB) + t;
#pragma unroll
        for (int o = 0; o < Oc; ++o) {
            const float4* wp = (const float4*)(wbase + o * (DOc * DIc));
            const float4 w0 = wp[0];
            const float4 w1 = wp[1];
            float u = w0.x * xa.x + w0.y * xa.y + w0.z * xa.z + w0.w * xa.w +
                      w1.x * xb.x + w1.y * xb.y + w1.z * xb.z + w1.w * xb.w;
            acc[o] += u;
            if (USE_WS) ubase[o * TPB] = u;
        }
    }
    block_reduce_squash(acc, 0.1f, red, svec, vcur, vsum, t, lane, wid);

    // ---------- Passes 1,2: routing ----------
    float vsr[Oc];
#pragma unroll 1
    for (int it = 1; it < 3; ++it) {
#pragma unroll
        for (int o = 0; o < Oc; ++o) vsr[o] = vsum[o * DOc + d];
#pragma unroll
        for (int o = 0; o < Oc; ++o) acc[o] = 0.f;

#pragma unroll 1
        for (int ch = 0; ch < CHUNKS; ++ch) {
            float uo[Oc];
            if (USE_WS) {
                const float* ubase =
                    uws + ((size_t)b * CHUNKS + ch) * (Oc * TPB) + t;
#pragma unroll
                for (int o = 0; o < Oc; ++o) uo[o] = ubase[o * TPB];
            } else {
                const int i = ch * 64 + iblk;
                const float4 xa = ((const float4*)(xs + i * DIc))[0];
                const float4 xb = ((const float4*)(xs + i * DIc))[1];
                const float* wbase = W + (((size_t)i * Oc) * DOc + d) * DIc;
#pragma unroll
                for (int o = 0; o < Oc; ++o) {
                    const float4* wp = (const float4*)(wbase + o * (DOc * DIc));
                    const float4 w0 = wp[0];
                    const float4 w1 = wp[1];
                    uo[o] = w0.x * xa.x + w0.y * xa.y + w0.z * xa.z + w0.w * xa.w +
                            w1.x * xb.x + w1.y * xb.y + w1.z * xb.z + w1.w * xb.w;
                }
            }
            // logits: c[o] = sum_d u[o,d] * vsum[o,d]  (reduce over 16-lane group)
            float c[Oc];
#pragma unroll
            for (int o = 0; o < Oc; ++o) {
                float p = uo[o] * vsr[o];
                p += __shfl_xor(p, 1);
                p += __shfl_xor(p, 2);
                p += __shfl_xor(p, 4);
                p += __shfl_xor(p, 8);
                c[o] = p;
            }
            // softmax over o (max-subtracted, as jax.nn.softmax)
            float m = c[0];
#pragma unroll
            for (int o = 1; o < Oc; ++o) m = fmaxf(m, c[o]);
            float se = 0.f;
#pragma unroll
            for (int o = 0; o < Oc; ++o) {
                c[o] = __expf(c[o] - m);
                se += c[o];
            }
            const float inv = 1.0f / se;
#pragma unroll
            for (int o = 0; o < Oc; ++o) acc[o] += (c[o] * inv) * uo[o];
        }
        block_reduce_squash(acc, 1.f, red, svec, vcur, vsum, t, lane, wid);
    }

    if (t < ODc) out[(size_t)b * ODc + t] = vcur[t];
}

extern "C" void kernel_launch(void* const* d_in, const int* in_sizes, int n_in,
                              void* d_out, int out_size, void* d_ws, size_t ws_size,
                              hipStream_t stream) {
    (void)in_sizes; (void)n_in; (void)out_size;
    const float* x = (const float*)d_in[0];   // [256,1152,8]
    const float* W = (const float*)d_in[1];   // [1152,10,16,8]
    float* out     = (float*)d_out;           // [256,10,16]
    float* uws     = (float*)d_ws;

    const size_t need = (size_t)Bc * CHUNKS * Oc * TPB * sizeof(float);  // ~189 MB
    dim3 grid(Bc), block(TPB);
    if (ws_size >= need) {
        hipLaunchKernelGGL((digitcaps_kernel<true>), grid, block, 0, stream,
                           x, W, out, uws);
    } else {
        hipLaunchKernelGGL((digitcaps_kernel<false>), grid, block, 0, stream,
                           x, W, out, nullptr);
    }
}

// Round 3
// 204.568 us; speedup vs baseline: 2.2991x; 1.3349x over previous
//
#include <hip/hip_runtime.h>
#include <hip/hip_fp16.h>
#include <math.h>

// DigitCaps dynamic routing, MI355X (gfx950).
// B=256, I=1152 (dim 8), O=10 (dim 16), 3 routing iters.
// Grid = 256 blocks (1/CU), block = 1024 threads (16 waves/CU).
//
// Lane mapping: t&15 = d (out dim), t>>4 = i-offset within a 64-capsule chunk.
// b_ij identity: logits at iter k = u . (v0+..+v_{k-1}) = u . vsum, so b_ij is
// never materialized.
//
// Round 3: u_hat workspace stored as fp16 (half2-packed over o-pairs).
//  - write traffic 189 -> 94.5 MB
//  - 94.5 MB working set fits the 256 MB Infinity Cache -> re-reads are LLC hits
//  - routing passes software-pipelined (prefetch next chunk's 5 dwords)
// Compute is fp32 throughout; only the ws round-trip is fp16.

constexpr int Bc  = 256;
constexpr int Ic  = 1152;
constexpr int DIc = 8;
constexpr int Oc  = 10;
constexpr int DOc = 16;
constexpr int ODc = Oc * DOc;       // 160
constexpr int TPB = 1024;           // 16 waves
constexpr int NW  = TPB / 64;       // 16
constexpr int CHUNKS = Ic / 64;     // 18 (exact)
constexpr int PAIRS  = Oc / 2;      // 5 half2 per thread per chunk

// Reduce acc[o] (per-lane, d = t&15 implicit) over i: 16-lane groups in the
// wave, then across 16 waves via LDS. Then squash along d.
__device__ __forceinline__ void block_reduce_squash(
    float* acc, float pre, float* red, float* svec, float* vcur, float* vsum,
    int t, int lane, int wid) {
#pragma unroll
    for (int o = 0; o < Oc; ++o) {
        float a = acc[o];
        a += __shfl_xor(a, 16);
        a += __shfl_xor(a, 32);
        if (lane < 16) red[wid * ODc + o * DOc + lane] = a;
    }
    __syncthreads();
    if (t < ODc) {
        float s = 0.f;
#pragma unroll
        for (int w = 0; w < NW; ++w) s += red[w * ODc + t];
        svec[t] = s * pre;
    }
    __syncthreads();
    if (t < Oc) {
        float sq = 0.f;
#pragma unroll
        for (int dd = 0; dd < DOc; ++dd) {
            float s = svec[t * DOc + dd];
            sq += s * s;
        }
        float scale = sq / ((1.f + sq) * sqrtf(sq));
#pragma unroll
        for (int dd = 0; dd < DOc; ++dd) {
            float v = svec[t * DOc + dd] * scale;
            vcur[t * DOc + dd] = v;
            vsum[t * DOc + dd] += v;
        }
    }
    __syncthreads();
}

template <bool USE_WS>
__global__ void __launch_bounds__(TPB, 4)
digitcaps_kernel(const float* __restrict__ x, const float* __restrict__ W,
                 float* __restrict__ out, __half2* __restrict__ uws) {
    const int b    = blockIdx.x;
    const int t    = threadIdx.x;
    const int lane = t & 63;
    const int wid  = t >> 6;
    const int d    = t & 15;
    const int iblk = t >> 4;     // 0..63: i-offset within chunk

    __shared__ __align__(16) float xs[Ic * DIc];   // 36 KB
    __shared__ __align__(16) float red[NW * ODc];  // 10 KB
    __shared__ __align__(16) float svec[ODc];
    __shared__ __align__(16) float vcur[ODc];
    __shared__ __align__(16) float vsum[ODc];

    // stage x[b] into LDS, coalesced float4
    {
        const float4* xg = (const float4*)(x + (size_t)b * (Ic * DIc));
        float4* xl = (float4*)xs;
        for (int j = t; j < Ic * DIc / 4; j += TPB) xl[j] = xg[j];
    }
    if (t < ODc) vsum[t] = 0.f;
    __syncthreads();

    float acc[Oc];

    // ---------- Pass 0: u = W@x ; s0 = 0.1 * sum_i u ; store fp16 u ----------
#pragma unroll
    for (int o = 0; o < Oc; ++o) acc[o] = 0.f;

    __half2* wsb = uws + (size_t)b * CHUNKS * PAIRS * TPB + t;

#pragma unroll 1
    for (int ch = 0; ch < CHUNKS; ++ch) {
        const int i = ch * 64 + iblk;
        const float4 xa = ((const float4*)(xs + i * DIc))[0];
        const float4 xb = ((const float4*)(xs + i * DIc))[1];
        const float* wbase = W + (((size_t)i * Oc) * DOc + d) * DIc;
        float u[Oc];
#pragma unroll
        for (int o = 0; o < Oc; ++o) {
            const float4* wp = (const float4*)(wbase + o * (DOc * DIc));
            const float4 w0 = wp[0];
            const float4 w1 = wp[1];
            u[o] = w0.x * xa.x + w0.y * xa.y + w0.z * xa.z + w0.w * xa.w +
                   w1.x * xb.x + w1.y * xb.y + w1.z * xb.z + w1.w * xb.w;
            acc[o] += u[o];
        }
        if (USE_WS) {
            __half2* ub = wsb + (size_t)ch * PAIRS * TPB;
#pragma unroll
            for (int op = 0; op < PAIRS; ++op)
                ub[op * TPB] = __floats2half2_rn(u[2 * op], u[2 * op + 1]);
        }
    }
    block_reduce_squash(acc, 0.1f, red, svec, vcur, vsum, t, lane, wid);

    // ---------- Passes 1,2: routing (software-pipelined ws reads) ----------
    float vsr[Oc];
#pragma unroll 1
    for (int it = 1; it < 3; ++it) {
#pragma unroll
        for (int o = 0; o < Oc; ++o) vsr[o] = vsum[o * DOc + d];
#pragma unroll
        for (int o = 0; o < Oc; ++o) acc[o] = 0.f;

        __half2 hb[PAIRS];
        if (USE_WS) {
#pragma unroll
            for (int op = 0; op < PAIRS; ++op) hb[op] = wsb[op * TPB];
        }

#pragma unroll 1
        for (int ch = 0; ch < CHUNKS; ++ch) {
            float uo[Oc];
            __half2 hn[PAIRS];
            if (USE_WS) {
                if (ch + 1 < CHUNKS) {
                    const __half2* nb = wsb + (size_t)(ch + 1) * PAIRS * TPB;
#pragma unroll
                    for (int op = 0; op < PAIRS; ++op) hn[op] = nb[op * TPB];
                }
#pragma unroll
                for (int op = 0; op < PAIRS; ++op) {
                    float2 f = __half22float2(hb[op]);
                    uo[2 * op]     = f.x;
                    uo[2 * op + 1] = f.y;
                }
            } else {
                const int i = ch * 64 + iblk;
                const float4 xa = ((const float4*)(xs + i * DIc))[0];
                const float4 xb = ((const float4*)(xs + i * DIc))[1];
                const float* wbase = W + (((size_t)i * Oc) * DOc + d) * DIc;
#pragma unroll
                for (int o = 0; o < Oc; ++o) {
                    const float4* wp = (const float4*)(wbase + o * (DOc * DIc));
                    const float4 w0 = wp[0];
                    const float4 w1 = wp[1];
                    uo[o] = w0.x * xa.x + w0.y * xa.y + w0.z * xa.z + w0.w * xa.w +
                            w1.x * xb.x + w1.y * xb.y + w1.z * xb.z + w1.w * xb.w;
                }
            }
            // logits: c[o] = sum_d u[o,d] * vsum[o,d]  (reduce over 16-lane group)
            float c[Oc];
#pragma unroll
            for (int o = 0; o < Oc; ++o) {
                float p = uo[o] * vsr[o];
                p += __shfl_xor(p, 1);
                p += __shfl_xor(p, 2);
                p += __shfl_xor(p, 4);
                p += __shfl_xor(p, 8);
                c[o] = p;
            }
            // softmax over o (max-subtracted, as jax.nn.softmax)
            float m = c[0];
#pragma unroll
            for (int o = 1; o < Oc; ++o) m = fmaxf(m, c[o]);
            float se = 0.f;
#pragma unroll
            for (int o = 0; o < Oc; ++o) {
                c[o] = __expf(c[o] - m);
                se += c[o];
            }
            const float inv = 1.0f / se;
#pragma unroll
            for (int o = 0; o < Oc; ++o) acc[o] += (c[o] * inv) * uo[o];

            if (USE_WS) {
#pragma unroll
                for (int op = 0; op < PAIRS; ++op) hb[op] = hn[op];
            }
        }
        block_reduce_squash(acc, 1.f, red, svec, vcur, vsum, t, lane, wid);
    }

    if (t < ODc) out[(size_t)b * ODc + t] = vcur[t];
}

extern "C" void kernel_launch(void* const* d_in, const int* in_sizes, int n_in,
                              void* d_out, int out_size, void* d_ws, size_t ws_size,
                              hipStream_t stream) {
    (void)in_sizes; (void)n_in; (void)out_size;
    const float* x = (const float*)d_in[0];   // [256,1152,8]
    const float* W = (const float*)d_in[1];   // [1152,10,16,8]
    float* out     = (float*)d_out;           // [256,10,16]
    __half2* uws   = (__half2*)d_ws;

    const size_t need = (size_t)Bc * CHUNKS * PAIRS * TPB * sizeof(__half2); // ~94.5 MB
    dim3 grid(Bc), block(TPB);
    if (ws_size >= need) {
        hipLaunchKernelGGL((digitcaps_kernel<true>), grid, block, 0, stream,
                           x, W, out, uws);
    } else {
        hipLaunchKernelGGL((digitcaps_kernel<false>), grid, block, 0, stream,
                           x, W, out, nullptr);
    }
}

// Round 4
// 181.991 us; speedup vs baseline: 2.5844x; 1.1241x over previous
//
#include <hip/hip_runtime.h>
#include <hip/hip_fp16.h>
#include <math.h>

// DigitCaps dynamic routing, MI355X (gfx950). Round 4: 6-kernel pipeline.
// B=256, I=1152 (dim 8), O=10 (dim 16), 3 routing iters.
//
// b_ij identity: logits at iter k = u . (v0+..+v_{k-1}) = u . vsum -> b_ij
// never materialized; vsum[256][160] lives in ws.
//
// K1  u_hat GEMM: grid 72 i-tiles x 16 b-tiles. Each thread holds its 80 W
//     floats in REGISTERS and reuses them over 16 b (fixes round-3's 1.5 GB
//     of duplicated W cache traffic -> 94 MB; same-itile blocks share an XCD).
//     Writes fp16 ws (94.4 MB) + s0 partials[72][256][160].
// K2  reduce 72 partials, *0.1, squash -> vsum = v0.
// K3  routing pass: grid 512 (b x half) x 1024 thr = 32 waves/CU; reads ws,
//     softmax(u.vsum), accumulates s partials[2][256][160].
// K4  reduce 2 partials, squash -> vsum += v1.
// K5  = K3 again.
// K6  reduce 2 partials, squash -> out = v2.

constexpr int Bc  = 256;
constexpr int Ic  = 1152;
constexpr int Oc  = 10;
constexpr int DOc = 16;
constexpr int ODc = 160;

// ---------------------------------------------------------------- K1
__global__ __launch_bounds__(256, 4) void k_uhat(const float* __restrict__ x,
                                                 const float* __restrict__ W,
                                                 __half2* __restrict__ uws,
                                                 float* __restrict__ partial) {
    const int bx    = blockIdx.x;
    const int itile = bx % 72;          // 72%8==0 -> same-itile blocks share XCD
    const int btile = bx / 72;          // 0..15
    const int t     = threadIdx.x;
    const int d     = t & 15;
    const int il    = t >> 4;           // 0..15
    const int w     = t >> 6;           // wave 0..3
    const int i     = itile * 16 + il;
    const int b0    = btile * 16;

    __shared__ __align__(16) float xs[16 * 128];        //  8 KB [bb][il*8+k]
    __shared__ __align__(16) float pacc[4 * 16 * ODc];  // 40 KB [w][bb][od]

    // stage x[b0:b0+16][itile*16:+16][8]
#pragma unroll
    for (int j = 0; j < 2; ++j) {
        int e  = t + j * 256;           // float4 index, 512 total
        int bb = e >> 5;
        int r  = e & 31;
        ((float4*)xs)[e] =
            ((const float4*)(x + (size_t)(b0 + bb) * (Ic * 8) + itile * 128))[r];
    }

    // W fragment for (i, d): 10 o x 8 k = 80 floats in registers
    float4 wr[20];
    {
        const float4* wp = (const float4*)(W + (((size_t)i * Oc) * DOc + d) * 8);
#pragma unroll
        for (int o = 0; o < Oc; ++o) {
            wr[2 * o]     = wp[o * 32];
            wr[2 * o + 1] = wp[o * 32 + 1];
        }
    }
    __syncthreads();

    const int ch    = i >> 6;
    const int off_t = (i & 63) * 16 + d;

#pragma unroll 1
    for (int bb = 0; bb < 16; ++bb) {
        const int b = b0 + bb;
        const float4 xa = *((const float4*)(xs + bb * 128 + il * 8));
        const float4 xb = *((const float4*)(xs + bb * 128 + il * 8 + 4));
        float u[Oc];
#pragma unroll
        for (int o = 0; o < Oc; ++o) {
            float4 w0 = wr[2 * o], w1 = wr[2 * o + 1];
            u[o] = w0.x * xa.x + w0.y * xa.y + w0.z * xa.z + w0.w * xa.w +
                   w1.x * xb.x + w1.y * xb.y + w1.z * xb.z + w1.w * xb.w;
        }
        // fp16 ws write, coalesced (off_t consecutive over t)
        __half2* ub = uws + ((size_t)b * 90 + ch * 5) * 1024 + off_t;
#pragma unroll
        for (int op = 0; op < 5; ++op)
            ub[op * 1024] = __floats2half2_rn(u[2 * op], u[2 * op + 1]);
        // reduce over the wave's 4 il values; lane<16 holds d
#pragma unroll
        for (int o = 0; o < Oc; ++o) {
            float a = u[o];
            a += __shfl_xor(a, 16);
            a += __shfl_xor(a, 32);
            if ((t & 63) < 16) pacc[(w * 16 + bb) * ODc + o * 16 + d] = a;
        }
    }
    __syncthreads();
    // partial[itile][b0+bb][od]
#pragma unroll
    for (int j = 0; j < 10; ++j) {
        int e = t + j * 256;            // bb*160+od, 2560 total
        float s = pacc[e] + pacc[2560 + e] + pacc[5120 + e] + pacc[7680 + e];
        partial[(size_t)itile * (Bc * ODc) + b0 * ODc + e] = s;
    }
}

// ---------------------------------------------------------------- K2/K4/K6
// MODE 0: vsum = v   MODE 1: vsum += v   MODE 2: out = v
template <int P, int MODE>
__global__ __launch_bounds__(256) void k_squash(const float* __restrict__ part,
                                                float* __restrict__ vsum,
                                                float* __restrict__ out,
                                                float pre) {
    const int b = blockIdx.x;
    const int t = threadIdx.x;
    if (t >= ODc) return;
    float s = 0.f;
#pragma unroll 8
    for (int p = 0; p < P; ++p) s += part[(size_t)p * (Bc * ODc) + b * ODc + t];
    s *= pre;
    float sq = s * s;
    sq += __shfl_xor(sq, 1);
    sq += __shfl_xor(sq, 2);
    sq += __shfl_xor(sq, 4);
    sq += __shfl_xor(sq, 8);
    float scale = sq / ((1.f + sq) * sqrtf(sq));
    float v = s * scale;
    if (MODE == 0) vsum[b * ODc + t] = v;
    if (MODE == 1) vsum[b * ODc + t] += v;
    if (MODE == 2) out[b * ODc + t] = v;
}

// ---------------------------------------------------------------- K3/K5
__global__ __launch_bounds__(1024, 8) void k_route(const __half2* __restrict__ uws,
                                                   const float* __restrict__ vsum,
                                                   float* __restrict__ spart) {
    const int bx  = blockIdx.x;
    const int b   = bx >> 1;
    const int h   = bx & 1;
    const int t   = threadIdx.x;
    const int d   = t & 15;
    const int wid = t >> 6;

    __shared__ float vs_s[ODc];
    __shared__ float red[16 * ODc];     // 10 KB
    if (t < ODc) vs_s[t] = vsum[b * ODc + t];
    __syncthreads();

    float vsr[Oc];
#pragma unroll
    for (int o = 0; o < Oc; ++o) vsr[o] = vs_s[o * 16 + d];
    float acc[Oc];
#pragma unroll
    for (int o = 0; o < Oc; ++o) acc[o] = 0.f;

    const __half2* wsb = uws + ((size_t)b * 90 + h * 45) * 1024 + t;
#pragma unroll 1
    for (int ch = 0; ch < 9; ++ch) {
        float uo[Oc];
#pragma unroll
        for (int op = 0; op < 5; ++op) {
            float2 f = __half22float2(wsb[(ch * 5 + op) * 1024]);
            uo[2 * op]     = f.x;
            uo[2 * op + 1] = f.y;
        }
        float c[Oc];
#pragma unroll
        for (int o = 0; o < Oc; ++o) {
            float p = uo[o] * vsr[o];
            p += __shfl_xor(p, 1);
            p += __shfl_xor(p, 2);
            p += __shfl_xor(p, 4);
            p += __shfl_xor(p, 8);
            c[o] = p;
        }
        float m = c[0];
#pragma unroll
        for (int o = 1; o < Oc; ++o) m = fmaxf(m, c[o]);
        float se = 0.f;
#pragma unroll
        for (int o = 0; o < Oc; ++o) {
            c[o] = __expf(c[o] - m);
            se += c[o];
        }
        const float inv = 1.f / se;
#pragma unroll
        for (int o = 0; o < Oc; ++o) acc[o] += (c[o] * inv) * uo[o];
    }
    // block reduce over iblk
#pragma unroll
    for (int o = 0; o < Oc; ++o) {
        float a = acc[o];
        a += __shfl_xor(a, 16);
        a += __shfl_xor(a, 32);
        if ((t & 63) < 16) red[wid * ODc + o * 16 + (t & 15)] = a;
    }
    __syncthreads();
    if (t < ODc) {
        float s = 0.f;
#pragma unroll
        for (int w = 0; w < 16; ++w) s += red[w * ODc + t];
        spart[(size_t)h * (Bc * ODc) + b * ODc + t] = s;
    }
}

// ---------------------------------------------------------------- fallback
// (round-3 structure, W-recompute, no ws) — used only if ws_size is tiny.
__global__ void __launch_bounds__(1024, 4)
digitcaps_fallback(const float* __restrict__ x, const float* __restrict__ W,
                   float* __restrict__ out) {
    const int b = blockIdx.x, t = threadIdx.x;
    const int lane = t & 63, wid = t >> 6, d = t & 15, iblk = t >> 4;
    __shared__ __align__(16) float xs[Ic * 8];
    __shared__ __align__(16) float red[16 * ODc];
    __shared__ __align__(16) float svec[ODc], vcur[ODc], vsum[ODc];
    {
        const float4* xg = (const float4*)(x + (size_t)b * (Ic * 8));
        float4* xl = (float4*)xs;
        for (int j = t; j < Ic * 2; j += 1024) xl[j] = xg[j];
    }
    if (t < ODc) vsum[t] = 0.f;
    __syncthreads();
    float acc[Oc], vsr[Oc];
    for (int it = 0; it < 3; ++it) {
#pragma unroll
        for (int o = 0; o < Oc; ++o) { acc[o] = 0.f; vsr[o] = vsum[o * 16 + d]; }
#pragma unroll 1
        for (int chk = 0; chk < 18; ++chk) {
            const int i = chk * 64 + iblk;
            const float4 xa = ((const float4*)(xs + i * 8))[0];
            const float4 xb = ((const float4*)(xs + i * 8))[1];
            const float* wb = W + (((size_t)i * Oc) * DOc + d) * 8;
            float uo[Oc];
#pragma unroll
            for (int o = 0; o < Oc; ++o) {
                const float4* wp = (const float4*)(wb + o * 128);
                float4 w0 = wp[0], w1 = wp[1];
                uo[o] = w0.x * xa.x + w0.y * xa.y + w0.z * xa.z + w0.w * xa.w +
                        w1.x * xb.x + w1.y * xb.y + w1.z * xb.z + w1.w * xb.w;
            }
            float cc[Oc];
            if (it > 0) {
#pragma unroll
                for (int o = 0; o < Oc; ++o) {
                    float p = uo[o] * vsr[o];
                    p += __shfl_xor(p, 1); p += __shfl_xor(p, 2);
                    p += __shfl_xor(p, 4); p += __shfl_xor(p, 8);
                    cc[o] = p;
                }
                float m = cc[0];
#pragma unroll
                for (int o = 1; o < Oc; ++o) m = fmaxf(m, cc[o]);
                float se = 0.f;
#pragma unroll
                for (int o = 0; o < Oc; ++o) { cc[o] = __expf(cc[o] - m); se += cc[o]; }
                float inv = 1.f / se;
#pragma unroll
                for (int o = 0; o < Oc; ++o) acc[o] += cc[o] * inv * uo[o];
            } else {
#pragma unroll
                for (int o = 0; o < Oc; ++o) acc[o] += 0.1f * uo[o];
            }
        }
#pragma unroll
        for (int o = 0; o < Oc; ++o) {
            float a = acc[o];
            a += __shfl_xor(a, 16);
            a += __shfl_xor(a, 32);
            if (lane < 16) red[wid * ODc + o * 16 + lane] = a;
        }
        __syncthreads();
        if (t < ODc) {
            float s = 0.f;
#pragma unroll
            for (int w = 0; w < 16; ++w) s += red[w * ODc + t];
            svec[t] = s;
        }
        __syncthreads();
        if (t < Oc) {
            float sq = 0.f;
#pragma unroll
            for (int dd = 0; dd < DOc; ++dd) sq += svec[t * 16 + dd] * svec[t * 16 + dd];
            float sc = sq / ((1.f + sq) * sqrtf(sq));
#pragma unroll
            for (int dd = 0; dd < DOc; ++dd) {
                float v = svec[t * 16 + dd] * sc;
                vcur[t * 16 + dd] = v;
                vsum[t * 16 + dd] += v;
            }
        }
        __syncthreads();
    }
    if (t < ODc) out[(size_t)b * ODc + t] = vcur[t];
}

// ---------------------------------------------------------------- launcher
extern "C" void kernel_launch(void* const* d_in, const int* in_sizes, int n_in,
                              void* d_out, int out_size, void* d_ws, size_t ws_size,
                              hipStream_t stream) {
    (void)in_sizes; (void)n_in; (void)out_size;
    const float* x = (const float*)d_in[0];   // [256,1152,8]
    const float* W = (const float*)d_in[1];   // [1152,10,16,8]
    float* out     = (float*)d_out;           // [256,10,16]

    const size_t UWS_B  = (size_t)Bc * 90 * 1024 * sizeof(__half2); // 94,371,840
    const size_t PART_B = (size_t)72 * Bc * ODc * sizeof(float);    // 11,796,480
    const size_t SPART_B = (size_t)2 * Bc * ODc * sizeof(float);    //    327,680
    const size_t VSUM_B  = (size_t)Bc * ODc * sizeof(float);        //    163,840

    __half2* uws   = (__half2*)d_ws;
    float* partial = (float*)((char*)d_ws + UWS_B);
    float* spart   = (float*)((char*)d_ws + UWS_B + PART_B);
    float* vsum    = (float*)((char*)d_ws + UWS_B + PART_B + SPART_B);

    if (ws_size >= UWS_B + PART_B + SPART_B + VSUM_B) {
        hipLaunchKernelGGL(k_uhat, dim3(1152), dim3(256), 0, stream, x, W, uws, partial);
        hipLaunchKernelGGL((k_squash<72, 0>), dim3(Bc), dim3(256), 0, stream,
                           partial, vsum, out, 0.1f);
        hipLaunchKernelGGL(k_route, dim3(512), dim3(1024), 0, stream, uws, vsum, spart);
        hipLaunchKernelGGL((k_squash<2, 1>), dim3(Bc), dim3(256), 0, stream,
                           spart, vsum, out, 1.f);
        hipLaunchKernelGGL(k_route, dim3(512), dim3(1024), 0, stream, uws, vsum, spart);
        hipLaunchKernelGGL((k_squash<2, 2>), dim3(Bc), dim3(256), 0, stream,
                           spart, vsum, out, 1.f);
    } else {
        hipLaunchKernelGGL(digitcaps_fallback, dim3(Bc), dim3(1024), 0, stream,
                           x, W, out);
    }
}